// Round 18
// baseline (101.197 us; speedup 1.0000x reference)
//
#include <hip/hip_runtime.h>
#include <hip/hip_bf16.h>
#include <math.h>

#define HIDDEN 1024
#define NSTATE 16
#define DTRANK 64
#define BB 2
#define SS 2048
#define ROWS (BB*SS)            // 4096
#define XPC 96                  // 2*STATE + DT_RANK
#define CH 256                  // chunks along S (occupancy lever for k_fused2)
#define CL 8                    // chunk length
#define BND (BB*NSTATE*HIDDEN)  // 32768
#define LOG2E 1.44269504088896f

#define RT 64                   // rows per k1 block
#define KSPL 8                  // K splits in k1
#define RX (ROWS*XPC)

typedef __hip_bfloat16 bf16;

// ---------------- K1: partial xp = x @ W_xproj, K-split (R17 exact) ----------------
__global__ __launch_bounds__(256) void k_xproj2(const float* __restrict__ x,
                                                const float* __restrict__ W,
                                                float* __restrict__ part) {
    __shared__ float xs[RT * 32];      // 8KB
    __shared__ float wt[96 * 36];      // 13.5KB
    int t  = threadIdx.x;
    int rt = blockIdx.x >> 3;
    int ks = blockIdx.x & 7;
    int r0 = rt * RT;
    int k0 = ks * 128;
    int cg = t & 15, rg = t >> 4;

    float acc[4][6];
    #pragma unroll
    for (int a = 0; a < 4; ++a)
        #pragma unroll
        for (int b = 0; b < 6; ++b) acc[a][b] = 0.f;

    for (int ch = 0; ch < 4; ++ch) {
        int kc = k0 + ch * 32;
        __syncthreads();
        #pragma unroll
        for (int m = 0; m < 2; ++m) {
            int e = t + m * 256;
            int row = e >> 3, kb = e & 7;
            float4 v = *(const float4*)&x[(r0 + row) * HIDDEN + kc + kb * 4];
            int kbp = kb ^ ((row >> 2) & 7);
            *(float4*)&xs[row * 32 + kbp * 4] = v;
        }
        #pragma unroll
        for (int m = 0; m < 3; ++m) {
            int f = t + m * 256;
            int kr = f / 24, cq = f % 24;
            float4 v = *(const float4*)&W[(kc + kr) * XPC + cq * 4];
            wt[(cq * 4 + 0) * 36 + kr] = v.x;
            wt[(cq * 4 + 1) * 36 + kr] = v.y;
            wt[(cq * 4 + 2) * 36 + kr] = v.z;
            wt[(cq * 4 + 3) * 36 + kr] = v.w;
        }
        __syncthreads();
        #pragma unroll
        for (int kg = 0; kg < 8; ++kg) {
            float4 wv[6], xv[4];
            #pragma unroll
            for (int j = 0; j < 6; ++j)
                wv[j] = *(float4*)&wt[(cg + 16 * j) * 36 + kg * 4];
            #pragma unroll
            for (int rr = 0; rr < 4; ++rr) {
                int row = rg * 4 + rr;
                xv[rr] = *(float4*)&xs[row * 32 + ((kg ^ ((row >> 2) & 7)) * 4)];
            }
            #pragma unroll
            for (int rr = 0; rr < 4; ++rr)
                #pragma unroll
                for (int j = 0; j < 6; ++j) {
                    acc[rr][j] = fmaf(xv[rr].x, wv[j].x, acc[rr][j]);
                    acc[rr][j] = fmaf(xv[rr].y, wv[j].y, acc[rr][j]);
                    acc[rr][j] = fmaf(xv[rr].z, wv[j].z, acc[rr][j]);
                    acc[rr][j] = fmaf(xv[rr].w, wv[j].w, acc[rr][j]);
                }
        }
    }
    #pragma unroll
    for (int rr = 0; rr < 4; ++rr)
        #pragma unroll
        for (int j = 0; j < 6; ++j)
            part[ks * RX + (r0 + rg * 4 + rr) * XPC + cg + 16 * j] = acc[rr][j];
}

// ---------------- K2: fused reduce + dt GEMM + pass1 ----------------
// block = (c, b, dblk); grid = 256*2*4 = 2048 blocks -> 8 blocks/CU.
__global__ __launch_bounds__(256)
void k_fused2(const float* __restrict__ part, const float* __restrict__ Wdt,
              const float* __restrict__ bdt, const float* __restrict__ x,
              const float* __restrict__ Alog, float* __restrict__ xp,
              bf16* __restrict__ dt, bf16* __restrict__ P,
              bf16* __restrict__ Q) {
    __shared__ float lxbm[CL * NSTATE];      // 8 x 16 Bm
    __shared__ float lxdt[CL * DTRANK];      // 8 x 64 dt-activations
    int t = threadIdx.x;
    int bid = blockIdx.x;
    int dblk = bid & 3;
    int b = (bid >> 2) & 1;
    int c = bid >> 3;
    int row0 = b * SS + c * CL;              // global row of chunk start
    int d = dblk * 256 + t;

    // --- phase A: reduce K-split partials for this chunk (8 rows x 96 cols) ---
    #pragma unroll
    for (int m = 0; m < CL * XPC / 256; ++m) {      // 3 elems/thread
        int e = t + m * 256;
        int rl = e / XPC, col = e % XPC;
        int gi = (row0 + rl) * XPC + col;
        float s = 0.f;
        #pragma unroll
        for (int p = 0; p < KSPL; ++p) s += part[p * RX + gi];
        if (col < NSTATE)            lxbm[rl * NSTATE + col] = s;
        else if (col >= 2 * NSTATE)  lxdt[rl * DTRANK + (col - 2 * NSTATE)] = s;
        if (dblk == 0) xp[gi] = s;           // one writer per (b,c)
    }
    __syncthreads();

    // --- phase B: dt GEMM, 8 rows in registers, k-outer for cross-row ILP ---
    float dtv[CL];
    {
        float bv = bdt[d];
        #pragma unroll
        for (int rr = 0; rr < CL; ++rr) dtv[rr] = bv;
        #pragma unroll
        for (int k = 0; k < DTRANK; k += 4) {
            float4 w;
            w.x = Wdt[(k + 0) * HIDDEN + d];
            w.y = Wdt[(k + 1) * HIDDEN + d];
            w.z = Wdt[(k + 2) * HIDDEN + d];
            w.w = Wdt[(k + 3) * HIDDEN + d];
            #pragma unroll
            for (int rr = 0; rr < CL; ++rr) {
                float4 a = *(float4*)&lxdt[rr * DTRANK + k];
                float acc = dtv[rr];
                acc = fmaf(a.x, w.x, acc);
                acc = fmaf(a.y, w.y, acc);
                acc = fmaf(a.z, w.z, acc);
                acc = fmaf(a.w, w.w, acc);
                dtv[rr] = acc;
            }
        }
        #pragma unroll
        for (int rr = 0; rr < CL; ++rr) {
            float a = dtv[rr];
            float o = fmaxf(a, 0.f) + __logf(1.f + __expf(-fabsf(a)));
            bf16 ob = __float2bfloat16(o);
            dt[(row0 + rr) * HIDDEN + d] = ob;         // for pass3
            dtv[rr] = __bfloat162float(ob);            // keep pass1 consistent with pass3
        }
    }

    // --- phase C: pass1 scan over the chunk ---
    float A2[NSTATE], Pv[NSTATE], Qv[NSTATE];
    #pragma unroll
    for (int n = 0; n < NSTATE; ++n) {
        A2[n] = -__expf(Alog[n*HIDDEN + d]) * LOG2E;
        Pv[n] = 1.f; Qv[n] = 0.f;
    }
    #pragma unroll
    for (int i = 0; i < CL; ++i) {
        float dv = dtv[i];
        float xv = x[(row0 + i) * HIDDEN + d];
        float bx = dv * xv;
        float bm[NSTATE];
        *(float4*)&bm[0]  = *(float4*)&lxbm[i * NSTATE + 0];
        *(float4*)&bm[4]  = *(float4*)&lxbm[i * NSTATE + 4];
        *(float4*)&bm[8]  = *(float4*)&lxbm[i * NSTATE + 8];
        *(float4*)&bm[12] = *(float4*)&lxbm[i * NSTATE + 12];
        #pragma unroll
        for (int n = 0; n < NSTATE; ++n) {
            float a = exp2f(A2[n] * dv);
            Qv[n] = fmaf(a, Qv[n], bm[n] * bx);
            Pv[n] *= a;
        }
    }
    int base = b * (NSTATE * HIDDEN) + d;
    #pragma unroll
    for (int n = 0; n < NSTATE; ++n) {
        P[c*BND + base + n*HIDDEN] = __float2bfloat16(Pv[n]);
        Q[c*BND + base + n*HIDDEN] = __float2bfloat16(Qv[n]);
    }
}

// ---------------- K3 (pass 2): serial scan over chunks; 64-thread blocks ----------------
__global__ __launch_bounds__(64)
void k_pass2(bf16* __restrict__ P, const bf16* __restrict__ Q) {
    int bnd = blockIdx.x * 64 + threadIdx.x;   // < 32768
    float h = 0.f;
    for (int cb = 0; cb < CH / 16; ++cb) {
        float p[16], q[16];
        #pragma unroll
        for (int j = 0; j < 16; ++j) {
            int idx = (cb*16 + j)*BND + bnd;
            p[j] = __bfloat162float(P[idx]);
            q[j] = __bfloat162float(Q[idx]);
        }
        #pragma unroll
        for (int j = 0; j < 16; ++j) {
            int idx = (cb*16 + j)*BND + bnd;
            P[idx] = __float2bfloat16(h);       // h_start for chunk
            h = fmaf(p[j], h, q[j]);
        }
    }
}

// ---------------- K4 (pass 3): re-run local scan from h_start, emit y ----------------
// grid = CH*BB*4 = 2048 blocks (8/CU)
__global__ __launch_bounds__(256, 4)
void k_pass3(const float* __restrict__ x, const bf16* __restrict__ dt,
             const float* __restrict__ xp, const float* __restrict__ Alog,
             const bf16* __restrict__ Hs, float* __restrict__ y) {
    int bid = blockIdx.x;
    int dblk = bid & 3;
    int b = (bid >> 2) & 1;
    int c = bid >> 3;
    int d = dblk * 256 + threadIdx.x;

    float A2[NSTATE], h[NSTATE];
    #pragma unroll
    for (int n = 0; n < NSTATE; ++n) {
        A2[n] = -__expf(Alog[n*HIDDEN + d]) * LOG2E;
        h[n] = __bfloat162float(Hs[c*BND + b*(NSTATE*HIDDEN) + n*HIDDEN + d]);
    }
    int s0 = c * CL;
    #pragma unroll
    for (int i = 0; i < CL; ++i) {
        int r = b*SS + s0 + i;
        float dv = __bfloat162float(dt[r*HIDDEN + d]);
        float xv = x[r*HIDDEN + d];
        float bx = dv * xv;
        float bm[NSTATE], cm[NSTATE];
        *(float4*)&bm[0]  = *(const float4*)&xp[r*XPC + 0];
        *(float4*)&bm[4]  = *(const float4*)&xp[r*XPC + 4];
        *(float4*)&bm[8]  = *(const float4*)&xp[r*XPC + 8];
        *(float4*)&bm[12] = *(const float4*)&xp[r*XPC + 12];
        *(float4*)&cm[0]  = *(const float4*)&xp[r*XPC + 16];
        *(float4*)&cm[4]  = *(const float4*)&xp[r*XPC + 20];
        *(float4*)&cm[8]  = *(const float4*)&xp[r*XPC + 24];
        *(float4*)&cm[12] = *(const float4*)&xp[r*XPC + 28];
        float yv = 0.f;
        #pragma unroll
        for (int n = 0; n < NSTATE; ++n) {
            float a = exp2f(A2[n] * dv);
            h[n] = fmaf(a, h[n], bm[n] * bx);
            yv = fmaf(cm[n], h[n], yv);
        }
        y[r*HIDDEN + d] = yv;
    }
}

extern "C" void kernel_launch(void* const* d_in, const int* in_sizes, int n_in,
                              void* d_out, int out_size, void* d_ws, size_t ws_size,
                              hipStream_t stream) {
    const float* x    = (const float*)d_in[0];
    const float* Wx   = (const float*)d_in[1];
    const float* Wdt  = (const float*)d_in[2];
    const float* bdt  = (const float*)d_in[3];
    const float* Alog = (const float*)d_in[4];
    float* y  = (float*)d_out;
    float* ws = (float*)d_ws;

    float* xp   = ws;                               // RX floats (1.5 MB)
    bf16*  dt   = (bf16*)(xp + RX);                 // ROWS*HIDDEN bf16 (8.4 MB)
    float* part = (float*)(dt + (size_t)ROWS*HIDDEN);   // KSPL*RX floats (12.6 MB)
    bf16*  P    = (bf16*)(part + (size_t)KSPL*RX);  // CH*BND bf16 (16.8 MB)
    bf16*  Q    = P + (size_t)CH*BND;               // 16.8 MB
    // total ws use: ~56 MB

    k_xproj2<<<(ROWS/RT)*KSPL, 256, 0, stream>>>(x, Wx, part);
    k_fused2<<<CH*BB*4, 256, 0, stream>>>(part, Wdt, bdt, x, Alog, xp, dt, P, Q);
    k_pass2<<<BND/64, 64, 0, stream>>>(P, Q);
    k_pass3<<<CH*BB*4, 256, 0, stream>>>(x, dt, xp, Alog, P, y);
}

// Round 19
// 95.593 us; speedup vs baseline: 1.0586x; 1.0586x over previous
//
#include <hip/hip_runtime.h>
#include <hip/hip_bf16.h>
#include <math.h>

#define HIDDEN 1024
#define NSTATE 16
#define DTRANK 64
#define BB 2
#define SS 2048
#define ROWS (BB*SS)            // 4096
#define XPC 96                  // 2*STATE + DT_RANK
#define CH 128                  // chunks along S (R17 operating point)
#define CL 16                   // chunk length
#define BND (BB*NSTATE*HIDDEN)  // 32768
#define LOG2E 1.44269504088896f

#define RT 64                   // rows per k1 block
#define KSPL 8                  // K splits in k1
#define RX (ROWS*XPC)

typedef __hip_bfloat16 bf16;

// ---------------- K1: partial xp = x @ W_xproj, K-split (R17 exact) ----------------
__global__ __launch_bounds__(256) void k_xproj2(const float* __restrict__ x,
                                                const float* __restrict__ W,
                                                float* __restrict__ part) {
    __shared__ float xs[RT * 32];      // 8KB
    __shared__ float wt[96 * 36];      // 13.5KB
    int t  = threadIdx.x;
    int rt = blockIdx.x >> 3;
    int ks = blockIdx.x & 7;
    int r0 = rt * RT;
    int k0 = ks * 128;
    int cg = t & 15, rg = t >> 4;

    float acc[4][6];
    #pragma unroll
    for (int a = 0; a < 4; ++a)
        #pragma unroll
        for (int b = 0; b < 6; ++b) acc[a][b] = 0.f;

    for (int ch = 0; ch < 4; ++ch) {
        int kc = k0 + ch * 32;
        __syncthreads();
        #pragma unroll
        for (int m = 0; m < 2; ++m) {
            int e = t + m * 256;
            int row = e >> 3, kb = e & 7;
            float4 v = *(const float4*)&x[(r0 + row) * HIDDEN + kc + kb * 4];
            int kbp = kb ^ ((row >> 2) & 7);
            *(float4*)&xs[row * 32 + kbp * 4] = v;
        }
        #pragma unroll
        for (int m = 0; m < 3; ++m) {
            int f = t + m * 256;
            int kr = f / 24, cq = f % 24;
            float4 v = *(const float4*)&W[(kc + kr) * XPC + cq * 4];
            wt[(cq * 4 + 0) * 36 + kr] = v.x;
            wt[(cq * 4 + 1) * 36 + kr] = v.y;
            wt[(cq * 4 + 2) * 36 + kr] = v.z;
            wt[(cq * 4 + 3) * 36 + kr] = v.w;
        }
        __syncthreads();
        #pragma unroll
        for (int kg = 0; kg < 8; ++kg) {
            float4 wv[6], xv[4];
            #pragma unroll
            for (int j = 0; j < 6; ++j)
                wv[j] = *(float4*)&wt[(cg + 16 * j) * 36 + kg * 4];
            #pragma unroll
            for (int rr = 0; rr < 4; ++rr) {
                int row = rg * 4 + rr;
                xv[rr] = *(float4*)&xs[row * 32 + ((kg ^ ((row >> 2) & 7)) * 4)];
            }
            #pragma unroll
            for (int rr = 0; rr < 4; ++rr)
                #pragma unroll
                for (int j = 0; j < 6; ++j) {
                    acc[rr][j] = fmaf(xv[rr].x, wv[j].x, acc[rr][j]);
                    acc[rr][j] = fmaf(xv[rr].y, wv[j].y, acc[rr][j]);
                    acc[rr][j] = fmaf(xv[rr].z, wv[j].z, acc[rr][j]);
                    acc[rr][j] = fmaf(xv[rr].w, wv[j].w, acc[rr][j]);
                }
        }
    }
    #pragma unroll
    for (int rr = 0; rr < 4; ++rr)
        #pragma unroll
        for (int j = 0; j < 6; ++j)
            part[ks * RX + (r0 + rg * 4 + rr) * XPC + cg + 16 * j] = acc[rr][j];
}

// ---------------- K2: fused reduce + dt GEMM + pass1 (R17 structure; bf16 dt store) ----------------
// block = (c, b, dblk); 1024 blocks x 256 threads -> 4 blocks/CU.
__global__ __launch_bounds__(256)
void k_fused2(const float* __restrict__ part, const float* __restrict__ Wdt,
              const float* __restrict__ bdt, const float* __restrict__ x,
              const float* __restrict__ Alog, float* __restrict__ xp,
              bf16* __restrict__ dt, bf16* __restrict__ P,
              bf16* __restrict__ Q) {
    __shared__ float lxbm[CL * NSTATE];      // 16 x 16 Bm, 1KB
    __shared__ float lxdt[CL * DTRANK];      // 16 x 64 dt-activations, 4KB
    int t = threadIdx.x;
    int bid = blockIdx.x;
    int dblk = bid & 3;
    int b = (bid >> 2) & 1;
    int c = bid >> 3;
    int row0 = b * SS + c * CL;              // global row of chunk start
    int d = dblk * 256 + t;

    // --- phase A: reduce K-split partials for this chunk (16 rows x 96 cols) ---
    #pragma unroll
    for (int m = 0; m < CL * XPC / 256; ++m) {      // 6 elems/thread
        int e = t + m * 256;
        int rl = e / XPC, col = e % XPC;
        int gi = (row0 + rl) * XPC + col;
        float s = 0.f;
        #pragma unroll
        for (int p = 0; p < KSPL; ++p) s += part[p * RX + gi];
        if (col < NSTATE)            lxbm[rl * NSTATE + col] = s;
        else if (col >= 2 * NSTATE)  lxdt[rl * DTRANK + (col - 2 * NSTATE)] = s;
        if (dblk == 0) xp[gi] = s;           // one writer per (b,c)
    }
    __syncthreads();

    // --- phase B: dt GEMM, 16 rows in registers, k-outer for cross-row ILP ---
    float dtv[CL];
    {
        float bv = bdt[d];
        #pragma unroll
        for (int rr = 0; rr < CL; ++rr) dtv[rr] = bv;
        #pragma unroll
        for (int k = 0; k < DTRANK; k += 4) {
            float4 w;
            w.x = Wdt[(k + 0) * HIDDEN + d];
            w.y = Wdt[(k + 1) * HIDDEN + d];
            w.z = Wdt[(k + 2) * HIDDEN + d];
            w.w = Wdt[(k + 3) * HIDDEN + d];
            #pragma unroll
            for (int rr = 0; rr < CL; ++rr) {
                float4 a = *(float4*)&lxdt[rr * DTRANK + k];
                float acc = dtv[rr];
                acc = fmaf(a.x, w.x, acc);
                acc = fmaf(a.y, w.y, acc);
                acc = fmaf(a.z, w.z, acc);
                acc = fmaf(a.w, w.w, acc);
                dtv[rr] = acc;
            }
        }
        #pragma unroll
        for (int rr = 0; rr < CL; ++rr) {
            float a = dtv[rr];
            float o = fmaxf(a, 0.f) + __logf(1.f + __expf(-fabsf(a)));
            bf16 ob = __float2bfloat16(o);
            dt[(row0 + rr) * HIDDEN + d] = ob;         // for pass3
            dtv[rr] = __bfloat162float(ob);            // keep pass1 consistent with pass3
        }
    }

    // --- phase C: pass1 scan over the chunk ---
    float A2[NSTATE], Pv[NSTATE], Qv[NSTATE];
    #pragma unroll
    for (int n = 0; n < NSTATE; ++n) {
        A2[n] = -__expf(Alog[n*HIDDEN + d]) * LOG2E;
        Pv[n] = 1.f; Qv[n] = 0.f;
    }
    #pragma unroll 2
    for (int i = 0; i < CL; ++i) {
        float dv = dtv[i];
        float xv = x[(row0 + i) * HIDDEN + d];
        float bx = dv * xv;
        float bm[NSTATE];
        *(float4*)&bm[0]  = *(float4*)&lxbm[i * NSTATE + 0];
        *(float4*)&bm[4]  = *(float4*)&lxbm[i * NSTATE + 4];
        *(float4*)&bm[8]  = *(float4*)&lxbm[i * NSTATE + 8];
        *(float4*)&bm[12] = *(float4*)&lxbm[i * NSTATE + 12];
        #pragma unroll
        for (int n = 0; n < NSTATE; ++n) {
            float a = exp2f(A2[n] * dv);
            Qv[n] = fmaf(a, Qv[n], bm[n] * bx);
            Pv[n] *= a;
        }
    }
    int base = b * (NSTATE * HIDDEN) + d;
    #pragma unroll
    for (int n = 0; n < NSTATE; ++n) {
        P[c*BND + base + n*HIDDEN] = __float2bfloat16(Pv[n]);
        Q[c*BND + base + n*HIDDEN] = __float2bfloat16(Qv[n]);
    }
}

// ---------------- K3 (pass 2): serial scan over chunks; 64-thread blocks (R17 exact) ----------------
__global__ __launch_bounds__(64)
void k_pass2(bf16* __restrict__ P, const bf16* __restrict__ Q) {
    int bnd = blockIdx.x * 64 + threadIdx.x;   // < 32768
    float h = 0.f;
    for (int cb = 0; cb < CH / 16; ++cb) {
        float p[16], q[16];
        #pragma unroll
        for (int j = 0; j < 16; ++j) {
            int idx = (cb*16 + j)*BND + bnd;
            p[j] = __bfloat162float(P[idx]);
            q[j] = __bfloat162float(Q[idx]);
        }
        #pragma unroll
        for (int j = 0; j < 16; ++j) {
            int idx = (cb*16 + j)*BND + bnd;
            P[idx] = __float2bfloat16(h);       // h_start for chunk
            h = fmaf(p[j], h, q[j]);
        }
    }
}

// ---------------- K4 (pass 3): re-run local scan from h_start, emit y ----------------
// grid = CH*BB*4 = 1024 blocks
__global__ __launch_bounds__(256, 4)
void k_pass3(const float* __restrict__ x, const bf16* __restrict__ dt,
             const float* __restrict__ xp, const float* __restrict__ Alog,
             const bf16* __restrict__ Hs, float* __restrict__ y) {
    int bid = blockIdx.x;
    int dblk = bid & 3;
    int b = (bid >> 2) & 1;
    int c = bid >> 3;
    int d = dblk * 256 + threadIdx.x;

    float A2[NSTATE], h[NSTATE];
    #pragma unroll
    for (int n = 0; n < NSTATE; ++n) {
        A2[n] = -__expf(Alog[n*HIDDEN + d]) * LOG2E;
        h[n] = __bfloat162float(Hs[c*BND + b*(NSTATE*HIDDEN) + n*HIDDEN + d]);
    }
    int s0 = c * CL;
    #pragma unroll 2
    for (int i = 0; i < CL; ++i) {
        int r = b*SS + s0 + i;
        float dv = __bfloat162float(dt[r*HIDDEN + d]);
        float xv = x[r*HIDDEN + d];
        float bx = dv * xv;
        float bm[NSTATE], cm[NSTATE];
        *(float4*)&bm[0]  = *(const float4*)&xp[r*XPC + 0];
        *(float4*)&bm[4]  = *(const float4*)&xp[r*XPC + 4];
        *(float4*)&bm[8]  = *(const float4*)&xp[r*XPC + 8];
        *(float4*)&bm[12] = *(const float4*)&xp[r*XPC + 12];
        *(float4*)&cm[0]  = *(const float4*)&xp[r*XPC + 16];
        *(float4*)&cm[4]  = *(const float4*)&xp[r*XPC + 20];
        *(float4*)&cm[8]  = *(const float4*)&xp[r*XPC + 24];
        *(float4*)&cm[12] = *(const float4*)&xp[r*XPC + 28];
        float yv = 0.f;
        #pragma unroll
        for (int n = 0; n < NSTATE; ++n) {
            float a = exp2f(A2[n] * dv);
            h[n] = fmaf(a, h[n], bm[n] * bx);
            yv = fmaf(cm[n], h[n], yv);
        }
        y[r*HIDDEN + d] = yv;
    }
}

extern "C" void kernel_launch(void* const* d_in, const int* in_sizes, int n_in,
                              void* d_out, int out_size, void* d_ws, size_t ws_size,
                              hipStream_t stream) {
    const float* x    = (const float*)d_in[0];
    const float* Wx   = (const float*)d_in[1];
    const float* Wdt  = (const float*)d_in[2];
    const float* bdt  = (const float*)d_in[3];
    const float* Alog = (const float*)d_in[4];
    float* y  = (float*)d_out;
    float* ws = (float*)d_ws;

    float* xp   = ws;                               // RX floats (1.5 MB)
    bf16*  dt   = (bf16*)(xp + RX);                 // ROWS*HIDDEN bf16 (8.4 MB)
    float* part = (float*)(dt + (size_t)ROWS*HIDDEN);   // KSPL*RX floats (12.6 MB)
    bf16*  P    = (bf16*)(part + (size_t)KSPL*RX);  // CH*BND bf16 (8.4 MB)
    bf16*  Q    = P + (size_t)CH*BND;               // 8.4 MB
    // total ws use: ~40 MB

    k_xproj2<<<(ROWS/RT)*KSPL, 256, 0, stream>>>(x, Wx, part);
    k_fused2<<<CH*BB*4, 256, 0, stream>>>(part, Wdt, bdt, x, Alog, xp, dt, P, Q);
    k_pass2<<<BND/64, 64, 0, stream>>>(P, Q);
    k_pass3<<<CH*BB*4, 256, 0, stream>>>(x, dt, xp, Alog, P, y);
}

// Round 20
// 95.093 us; speedup vs baseline: 1.0642x; 1.0053x over previous
//
#include <hip/hip_runtime.h>
#include <hip/hip_bf16.h>
#include <math.h>

#define HIDDEN 1024
#define NSTATE 16
#define DTRANK 64
#define BB 2
#define SS 2048
#define ROWS (BB*SS)            // 4096
#define XPC 96                  // 2*STATE + DT_RANK
#define CH 128                  // chunks along S
#define CL 16                   // chunk length
#define BND (BB*NSTATE*HIDDEN)  // 32768
#define LOG2E 1.44269504088896f

#define RT 64                   // rows per k1 block
#define KSPL 8                  // K splits in k1
#define RX (ROWS*XPC)

typedef __hip_bfloat16 bf16;

// ---------------- K1: partial xp = x @ W_xproj, K-split ----------------
__global__ __launch_bounds__(256) void k_xproj2(const float* __restrict__ x,
                                                const float* __restrict__ W,
                                                float* __restrict__ part) {
    __shared__ float xs[RT * 32];      // 8KB
    __shared__ float wt[96 * 36];      // 13.5KB
    int t  = threadIdx.x;
    int rt = blockIdx.x >> 3;
    int ks = blockIdx.x & 7;
    int r0 = rt * RT;
    int k0 = ks * 128;
    int cg = t & 15, rg = t >> 4;

    float acc[4][6];
    #pragma unroll
    for (int a = 0; a < 4; ++a)
        #pragma unroll
        for (int b = 0; b < 6; ++b) acc[a][b] = 0.f;

    for (int ch = 0; ch < 4; ++ch) {
        int kc = k0 + ch * 32;
        __syncthreads();
        #pragma unroll
        for (int m = 0; m < 2; ++m) {
            int e = t + m * 256;
            int row = e >> 3, kb = e & 7;
            float4 v = *(const float4*)&x[(r0 + row) * HIDDEN + kc + kb * 4];
            int kbp = kb ^ ((row >> 2) & 7);
            *(float4*)&xs[row * 32 + kbp * 4] = v;
        }
        #pragma unroll
        for (int m = 0; m < 3; ++m) {
            int f = t + m * 256;
            int kr = f / 24, cq = f % 24;
            float4 v = *(const float4*)&W[(kc + kr) * XPC + cq * 4];
            wt[(cq * 4 + 0) * 36 + kr] = v.x;
            wt[(cq * 4 + 1) * 36 + kr] = v.y;
            wt[(cq * 4 + 2) * 36 + kr] = v.z;
            wt[(cq * 4 + 3) * 36 + kr] = v.w;
        }
        __syncthreads();
        #pragma unroll
        for (int kg = 0; kg < 8; ++kg) {
            float4 wv[6], xv[4];
            #pragma unroll
            for (int j = 0; j < 6; ++j)
                wv[j] = *(float4*)&wt[(cg + 16 * j) * 36 + kg * 4];
            #pragma unroll
            for (int rr = 0; rr < 4; ++rr) {
                int row = rg * 4 + rr;
                xv[rr] = *(float4*)&xs[row * 32 + ((kg ^ ((row >> 2) & 7)) * 4)];
            }
            #pragma unroll
            for (int rr = 0; rr < 4; ++rr)
                #pragma unroll
                for (int j = 0; j < 6; ++j) {
                    acc[rr][j] = fmaf(xv[rr].x, wv[j].x, acc[rr][j]);
                    acc[rr][j] = fmaf(xv[rr].y, wv[j].y, acc[rr][j]);
                    acc[rr][j] = fmaf(xv[rr].z, wv[j].z, acc[rr][j]);
                    acc[rr][j] = fmaf(xv[rr].w, wv[j].w, acc[rr][j]);
                }
        }
    }
    #pragma unroll
    for (int rr = 0; rr < 4; ++rr)
        #pragma unroll
        for (int j = 0; j < 6; ++j)
            part[ks * RX + (r0 + rg * 4 + rr) * XPC + cg + 16 * j] = acc[rr][j];
}

// ---------------- K2: fused reduce + dt GEMM + pass1 (bf16 P/Q stores) ----------------
// block = (c, b, dblk); 1024 blocks x 256 threads -> 4 blocks/CU.
__global__ __launch_bounds__(256)
void k_fused2(const float* __restrict__ part, const float* __restrict__ Wdt,
              const float* __restrict__ bdt, const float* __restrict__ x,
              const float* __restrict__ Alog, float* __restrict__ xp,
              float* __restrict__ dt, bf16* __restrict__ P,
              bf16* __restrict__ Q) {
    __shared__ float lxbm[CL * NSTATE];      // 16 x 16 Bm, 1KB
    __shared__ float lxdt[CL * DTRANK];      // 16 x 64 dt-activations, 4KB
    int t = threadIdx.x;
    int bid = blockIdx.x;
    int dblk = bid & 3;
    int b = (bid >> 2) & 1;
    int c = bid >> 3;
    int row0 = b * SS + c * CL;              // global row of chunk start
    int d = dblk * 256 + t;

    // --- phase A: reduce K-split partials for this chunk (16 rows x 96 cols) ---
    #pragma unroll
    for (int m = 0; m < CL * XPC / 256; ++m) {      // 6 elems/thread
        int e = t + m * 256;
        int rl = e / XPC, col = e % XPC;
        int gi = (row0 + rl) * XPC + col;
        float s = 0.f;
        #pragma unroll
        for (int p = 0; p < KSPL; ++p) s += part[p * RX + gi];
        if (col < NSTATE)            lxbm[rl * NSTATE + col] = s;
        else if (col >= 2 * NSTATE)  lxdt[rl * DTRANK + (col - 2 * NSTATE)] = s;
        if (dblk == 0) xp[gi] = s;           // one writer per (b,c)
    }
    __syncthreads();

    // --- phase B: dt GEMM, 16 rows in registers, k-outer for cross-row ILP ---
    float dtv[CL];
    {
        float bv = bdt[d];
        #pragma unroll
        for (int rr = 0; rr < CL; ++rr) dtv[rr] = bv;
        #pragma unroll
        for (int k = 0; k < DTRANK; k += 4) {
            float4 w;
            w.x = Wdt[(k + 0) * HIDDEN + d];
            w.y = Wdt[(k + 1) * HIDDEN + d];
            w.z = Wdt[(k + 2) * HIDDEN + d];
            w.w = Wdt[(k + 3) * HIDDEN + d];
            #pragma unroll
            for (int rr = 0; rr < CL; ++rr) {
                float4 a = *(float4*)&lxdt[rr * DTRANK + k];
                float acc = dtv[rr];
                acc = fmaf(a.x, w.x, acc);
                acc = fmaf(a.y, w.y, acc);
                acc = fmaf(a.z, w.z, acc);
                acc = fmaf(a.w, w.w, acc);
                dtv[rr] = acc;
            }
        }
        #pragma unroll
        for (int rr = 0; rr < CL; ++rr) {
            float a = dtv[rr];
            float o = fmaxf(a, 0.f) + __logf(1.f + __expf(-fabsf(a)));
            dtv[rr] = o;
            dt[(row0 + rr) * HIDDEN + d] = o;   // for pass3
        }
    }

    // --- phase C: pass1 scan over the chunk ---
    float A2[NSTATE], Pv[NSTATE], Qv[NSTATE];
    #pragma unroll
    for (int n = 0; n < NSTATE; ++n) {
        A2[n] = -__expf(Alog[n*HIDDEN + d]) * LOG2E;
        Pv[n] = 1.f; Qv[n] = 0.f;
    }
    #pragma unroll 2
    for (int i = 0; i < CL; ++i) {
        float dv = dtv[i];
        float xv = x[(row0 + i) * HIDDEN + d];
        float bx = dv * xv;
        float bm[NSTATE];
        *(float4*)&bm[0]  = *(float4*)&lxbm[i * NSTATE + 0];
        *(float4*)&bm[4]  = *(float4*)&lxbm[i * NSTATE + 4];
        *(float4*)&bm[8]  = *(float4*)&lxbm[i * NSTATE + 8];
        *(float4*)&bm[12] = *(float4*)&lxbm[i * NSTATE + 12];
        #pragma unroll
        for (int n = 0; n < NSTATE; ++n) {
            float a = exp2f(A2[n] * dv);
            Qv[n] = fmaf(a, Qv[n], bm[n] * bx);
            Pv[n] *= a;
        }
    }
    int base = b * (NSTATE * HIDDEN) + d;
    #pragma unroll
    for (int n = 0; n < NSTATE; ++n) {
        P[c*BND + base + n*HIDDEN] = __float2bfloat16(Pv[n]);
        Q[c*BND + base + n*HIDDEN] = __float2bfloat16(Qv[n]);
    }
}

// ---------------- K3 (pass 2): serial scan over chunks; 64-thread blocks (all CUs) ----------------
__global__ __launch_bounds__(64)
void k_pass2(bf16* __restrict__ P, const bf16* __restrict__ Q) {
    int bnd = blockIdx.x * 64 + threadIdx.x;   // < 32768
    float h = 0.f;
    for (int cb = 0; cb < CH / 16; ++cb) {
        float p[16], q[16];
        #pragma unroll
        for (int j = 0; j < 16; ++j) {
            int idx = (cb*16 + j)*BND + bnd;
            p[j] = __bfloat162float(P[idx]);
            q[j] = __bfloat162float(Q[idx]);
        }
        #pragma unroll
        for (int j = 0; j < 16; ++j) {
            int idx = (cb*16 + j)*BND + bnd;
            P[idx] = __float2bfloat16(h);       // h_start for chunk
            h = fmaf(p[j], h, q[j]);
        }
    }
}

// ---------------- K4 (pass 3): re-run local scan from h_start, emit y ----------------
// grid = CH*BB*4 = 1024 blocks
__global__ __launch_bounds__(256, 4)
void k_pass3(const float* __restrict__ x, const float* __restrict__ dt,
             const float* __restrict__ xp, const float* __restrict__ Alog,
             const bf16* __restrict__ Hs, float* __restrict__ y) {
    int bid = blockIdx.x;
    int dblk = bid & 3;
    int b = (bid >> 2) & 1;
    int c = bid >> 3;
    int d = dblk * 256 + threadIdx.x;

    float A2[NSTATE], h[NSTATE];
    #pragma unroll
    for (int n = 0; n < NSTATE; ++n) {
        A2[n] = -__expf(Alog[n*HIDDEN + d]) * LOG2E;
        h[n] = __bfloat162float(Hs[c*BND + b*(NSTATE*HIDDEN) + n*HIDDEN + d]);
    }
    int s0 = c * CL;
    #pragma unroll 2
    for (int i = 0; i < CL; ++i) {
        int r = b*SS + s0 + i;
        float dv = dt[r*HIDDEN + d];
        float xv = x[r*HIDDEN + d];
        float bx = dv * xv;
        float bm[NSTATE], cm[NSTATE];
        *(float4*)&bm[0]  = *(const float4*)&xp[r*XPC + 0];
        *(float4*)&bm[4]  = *(const float4*)&xp[r*XPC + 4];
        *(float4*)&bm[8]  = *(const float4*)&xp[r*XPC + 8];
        *(float4*)&bm[12] = *(const float4*)&xp[r*XPC + 12];
        *(float4*)&cm[0]  = *(const float4*)&xp[r*XPC + 16];
        *(float4*)&cm[4]  = *(const float4*)&xp[r*XPC + 20];
        *(float4*)&cm[8]  = *(const float4*)&xp[r*XPC + 24];
        *(float4*)&cm[12] = *(const float4*)&xp[r*XPC + 28];
        float yv = 0.f;
        #pragma unroll
        for (int n = 0; n < NSTATE; ++n) {
            float a = exp2f(A2[n] * dv);
            h[n] = fmaf(a, h[n], bm[n] * bx);
            yv = fmaf(cm[n], h[n], yv);
        }
        y[r*HIDDEN + d] = yv;
    }
}

extern "C" void kernel_launch(void* const* d_in, const int* in_sizes, int n_in,
                              void* d_out, int out_size, void* d_ws, size_t ws_size,
                              hipStream_t stream) {
    const float* x    = (const float*)d_in[0];
    const float* Wx   = (const float*)d_in[1];
    const float* Wdt  = (const float*)d_in[2];
    const float* bdt  = (const float*)d_in[3];
    const float* Alog = (const float*)d_in[4];
    float* y  = (float*)d_out;
    float* ws = (float*)d_ws;

    float* xp   = ws;                               // RX floats (1.5 MB)
    float* dt   = xp + RX;                          // ROWS*HIDDEN floats (16.8 MB)
    float* part = dt + (size_t)ROWS*HIDDEN;         // KSPL*RX floats (12.6 MB)
    bf16*  P    = (bf16*)(part + (size_t)KSPL*RX);  // CH*BND bf16 (8.4 MB)
    bf16*  Q    = P + (size_t)CH*BND;               // 8.4 MB
    // total ws use: ~48 MB

    k_xproj2<<<(ROWS/RT)*KSPL, 256, 0, stream>>>(x, Wx, part);
    k_fused2<<<CH*BB*4, 256, 0, stream>>>(part, Wdt, bdt, x, Alog, xp, dt, P, Q);
    k_pass2<<<BND/64, 64, 0, stream>>>(P, Q);
    k_pass3<<<CH*BB*4, 256, 0, stream>>>(x, dt, xp, Alog, P, y);
}